// Round 4
// baseline (813.398 us; speedup 1.0000x reference)
//
#include <hip/hip_runtime.h>
#include <hip/hip_bf16.h>

#define NEI     128
#define NUM_REL 5000
#define NSUP    32
#define D       128
#define K_TOP   64
#define NB      256
#define ROWSZ   (K_TOP * D)   // 8192

// d_out layout (FLOAT32 elements), outputs concatenated flat in return order
#define TN_OFF  0           // tree_node      [256][3][64]
#define TE_OFF  49152       // tree_emb_all   [256][3][64][128]
#define PI_OFF  6340608     // parent_index   [256][3][64]
#define PN_OFF  6389760     // parent_node    [256][3][64]
#define AR_OFF  6438912     // aim_rel_all    [256][3][64]

#define SENT 0xFFFFFFFFu

typedef __hip_bfloat16 bf16;
__device__ __forceinline__ float frbf(bf16 b) { return __bfloat162float(b); }
__device__ __forceinline__ float b2f(unsigned short u) {
    unsigned x = ((unsigned)u) << 16;
    return __uint_as_float(x);
}
__device__ __forceinline__ unsigned umin2(unsigned a, unsigned b) { return a < b ? a : b; }

// Flag-dispatched float-input load: storage is either f32 or packed bf16.
__device__ __forceinline__ float ldin(const void* p, size_t idx, bool isbf) {
    return isbf ? frbf(((const bf16*)p)[idx]) : ((const float*)p)[idx];
}

// Detect storage dtype of float-family inputs (probe cosm); whole-block call.
__device__ __forceinline__ void detect_bf16(const void* probe, int tid, int* s_flag) {
    if (tid < 64) {
        unsigned w = ((const unsigned*)probe)[tid];
        unsigned e = (w >> 7) & 0xFFu;
        unsigned long long m = __ballot(e >= 100 && e <= 135);
        if (tid == 0) *s_flag = (__popcll(m) >= 48) ? 1 : 0;
    }
    __syncthreads();
}

// Barrier-free 64x384 GEMM inner loop, 768-thread variant: X (64x128) in LDS,
// W (384x128) streamed from global (L2-hot). Thread (gi_,gj) with gj in 0..95
// accumulates acc[m][n] = dot(X[gi_+8m], W[gj+96n]). FP order per output is
// identical to the verified kernel (k ascending, float4 chunks, dot4 per add).
__device__ __forceinline__ void gemm_8x4(const float* hs, const void* W,
                                         bool isbf, int gi_, int gj,
                                         float acc[8][4]) {
    if (!isbf) {
        const float* Wf = (const float*)W;
        #pragma unroll 2
        for (int kt = 0; kt < D; kt += 4) {
            float4 hv[8], wv[4];
            #pragma unroll
            for (int n = 0; n < 4; n++)
                wv[n] = *(const float4*)&Wf[(size_t)(gj + 96 * n) * D + kt];
            #pragma unroll
            for (int m = 0; m < 8; m++)
                hv[m] = *(const float4*)&hs[(gi_ + 8 * m) * 132 + kt];
            #pragma unroll
            for (int m = 0; m < 8; m++)
                #pragma unroll
                for (int n = 0; n < 4; n++)
                    acc[m][n] += hv[m].x * wv[n].x + hv[m].y * wv[n].y
                               + hv[m].z * wv[n].z + hv[m].w * wv[n].w;
        }
    } else {
        const ushort* Wb = (const ushort*)W;
        #pragma unroll 2
        for (int kt = 0; kt < D; kt += 4) {
            float4 hv[8], wv[4];
            #pragma unroll
            for (int n = 0; n < 4; n++) {
                ushort4 t = *(const ushort4*)&Wb[(size_t)(gj + 96 * n) * D + kt];
                wv[n].x = b2f(t.x); wv[n].y = b2f(t.y);
                wv[n].z = b2f(t.z); wv[n].w = b2f(t.w);
            }
            #pragma unroll
            for (int m = 0; m < 8; m++)
                hv[m] = *(const float4*)&hs[(gi_ + 8 * m) * 132 + kt];
            #pragma unroll
            for (int m = 0; m < 8; m++)
                #pragma unroll
                for (int n = 0; n < 4; n++)
                    acc[m][n] += hv[m].x * wv[n].x + hv[m].y * wv[n].y
                               + hv[m].z * wv[n].z + hv[m].w * wv[n].w;
        }
    }
}

// ---------------------------------------------------------------------------
// rank[r] = #{r' : maxscore[r'] > maxscore[r]} (ties share rank ->
// key (rank<<13|idx) reproduces jax.lax.top_k ordering exactly).
// Vectorized: ms computed 4 cols/thread (float4/ushort4 loads, 16B/8B per
// lane coalesced); count loop reads ms as float4 (1250 ds_read_b128).
__global__ __launch_bounds__(256) void k_rank(const int* __restrict__ support,
                                              const void* __restrict__ cosm,
                                              int* __restrict__ rnk) {
    __shared__ __align__(16) float ms[NUM_REL];
    __shared__ int sup[NSUP];
    __shared__ int s_isbf;
    const int tid = threadIdx.x;
    detect_bf16(cosm, tid, &s_isbf);
    const bool isbf = (bool)s_isbf;
    if (tid < NSUP) sup[tid] = support[tid];
    __syncthreads();

    float4* ms4 = (float4*)ms;
    const int NC4 = NUM_REL / 4;  // 1250, exact
    if (!isbf) {
        const float* cf = (const float*)cosm;
        for (int i4 = tid; i4 < NC4; i4 += 256) {
            float4 m = make_float4(-INFINITY, -INFINITY, -INFINITY, -INFINITY);
            #pragma unroll
            for (int s = 0; s < NSUP; s++) {
                float4 v = *(const float4*)&cf[(size_t)sup[s] * NUM_REL + i4 * 4];
                m.x = fmaxf(m.x, v.x); m.y = fmaxf(m.y, v.y);
                m.z = fmaxf(m.z, v.z); m.w = fmaxf(m.w, v.w);
            }
            ms4[i4] = m;
        }
    } else {
        const ushort* cb = (const ushort*)cosm;
        for (int i4 = tid; i4 < NC4; i4 += 256) {
            float4 m = make_float4(-INFINITY, -INFINITY, -INFINITY, -INFINITY);
            #pragma unroll
            for (int s = 0; s < NSUP; s++) {
                ushort4 t = *(const ushort4*)&cb[(size_t)sup[s] * NUM_REL + i4 * 4];
                m.x = fmaxf(m.x, b2f(t.x)); m.y = fmaxf(m.y, b2f(t.y));
                m.z = fmaxf(m.z, b2f(t.z)); m.w = fmaxf(m.w, b2f(t.w));
            }
            ms4[i4] = m;
        }
    }
    __syncthreads();

    int r = blockIdx.x * 256 + tid;
    if (r < NUM_REL) {
        float mine = ms[r];
        int c = 0;
        for (int i4 = 0; i4 < NC4; i4++) {
            float4 v = ms4[i4];
            c += (v.x > mine) + (v.y > mine) + (v.z > mine) + (v.w > mine);
        }
        rnk[r] = c;
    }
}

// ---------------------------------------------------------------------------
// Level-1 selection only: 128 candidates -> stable top-64 via bitonic sort.
__global__ __launch_bounds__(256) void k_expand1(
    const int* __restrict__ query, const int* __restrict__ edge,
    const int* __restrict__ rnk, float* __restrict__ out)
{
    __shared__ unsigned keys[NEI];
    __shared__ int2 pairs[NEI];
    const int tid = threadIdx.x;
    const int b = blockIdx.x;
    const int q = query[b];

    if (tid < NEI) {
        int2 pr = ((const int2*)edge)[(size_t)q * NEI + tid];
        pairs[tid] = pr;
        keys[tid] = ((unsigned)rnk[pr.y] << 13) | (unsigned)tid;
    }
    for (int size = 2; size <= NEI; size <<= 1) {
        for (int stride = size >> 1; stride > 0; stride >>= 1) {
            __syncthreads();
            if (tid < NEI) {
                int partner = tid ^ stride;
                if (partner > tid) {
                    unsigned a = keys[tid], c2 = keys[partner];
                    bool asc = ((tid & size) == 0);
                    if (asc ? (a > c2) : (a < c2)) { keys[tid] = c2; keys[partner] = a; }
                }
            }
        }
    }
    __syncthreads();
    if (tid < K_TOP) {
        int idx = keys[tid] & 8191;
        int2 p = pairs[idx];
        float* su = out + TE_OFF + ((size_t)b * 3 + 1) * ROWSZ;
        su[tid]         = (float)p.x;   // e1 (exact in f32)
        su[K_TOP + tid] = (float)p.y;   // r1
        out[TN_OFF + (b * 3 + 0) * K_TOP + tid] = (float)p.x;
        out[PN_OFF + (b * 3 + 0) * K_TOP + tid] = (float)q;
        out[PI_OFF + (b * 3 + 2) * K_TOP + tid] = (float)tid;  // arange row
    }
}

// ---------------------------------------------------------------------------
// Levels 2/3 selection: 8192 candidates -> top-64 (register keys, iterative
// block-min). Level 2 stashes (e2,r2) in TE row 2 head.
__global__ __launch_bounds__(384) void k_expand(
    const int* __restrict__ edge, const int* __restrict__ rnk,
    float* __restrict__ out, const int level)
{
    __shared__ int pe[K_TOP], prl[K_TOP];
    __shared__ unsigned topks[K_TOP];
    __shared__ unsigned wred[6];

    const int tid = threadIdx.x;
    const int b = blockIdx.x;
    const int2* edge2 = (const int2*)edge;

    if (tid < K_TOP) {
        const float* su = out + TE_OFF + ((size_t)b * 3 + (level - 1)) * ROWSZ;
        pe[tid]  = (int)su[tid];
        prl[tid] = (int)su[K_TOP + tid];
    }
    __syncthreads();

    unsigned kreg[22];
    #pragma unroll
    for (int i = 0; i < 22; i++) {
        int j = tid + i * 384;
        unsigned k = SENT;
        if (j < K_TOP * NEI) {
            int rel = edge2[(size_t)pe[j >> 7] * NEI + (j & 127)].y;
            k = ((unsigned)rnk[rel] << 13) | (unsigned)j;
        }
        kreg[i] = k;
    }
    unsigned lmin = SENT;
    #pragma unroll
    for (int i = 0; i < 22; i++) lmin = umin2(lmin, kreg[i]);

    const int wid = tid >> 6;
    for (int it = 0; it < K_TOP; it++) {
        unsigned m = lmin;
        #pragma unroll
        for (int off = 32; off > 0; off >>= 1)
            m = umin2(m, (unsigned)__shfl_xor((int)m, off, 64));
        if ((tid & 63) == 0) wred[wid] = m;
        __syncthreads();
        unsigned g = umin2(umin2(umin2(wred[0], wred[1]), umin2(wred[2], wred[3])),
                           umin2(wred[4], wred[5]));
        if (tid == 0) topks[it] = g;
        if (lmin == g) {
            unsigned nl = SENT;
            #pragma unroll
            for (int i = 0; i < 22; i++) {
                if (kreg[i] == g) kreg[i] = SENT;
                nl = umin2(nl, kreg[i]);
            }
            lmin = nl;
        }
        __syncthreads();
    }

    if (tid < K_TOP) {
        int j = topks[tid] & 8191;
        int p = j >> 7, t = j & 127;
        int2 pr2 = edge2[(size_t)pe[p] * NEI + t];
        const int L1 = level - 1;
        out[TN_OFF + (b * 3 + L1) * K_TOP + tid]          = (float)pr2.x;
        out[PI_OFF + (b * 3 + (level - 2)) * K_TOP + tid] = (float)p;
        out[PN_OFF + (b * 3 + L1) * K_TOP + tid]          = (float)pe[p];
        out[AR_OFF + (b * 3 + (level - 2)) * K_TOP + tid] = (float)prl[p];
        if (level == 3)
            out[AR_OFF + (b * 3 + 2) * K_TOP + tid]       = (float)pr2.y;
        if (level == 2) {
            float* su = out + TE_OFF + ((size_t)b * 3 + 2) * ROWSZ;
            su[tid]         = (float)pr2.x;
            su[K_TOP + tid] = (float)pr2.y;
        }
    }
}

// ---------------------------------------------------------------------------
// GRU for one level. ONE 768-thread block per batch (12 waves co-resident on
// one CU by construction — a block's waves always launch together). Each
// thread owns 8x4 outputs -> ~80 live VGPRs, giving the compiler headroom to
// pipeline the global W stream. K-loops remain barrier-free.
__global__ __launch_bounds__(768) void k_gru(
    const void* __restrict__ rel_emb,
    const void* __restrict__ W_ih, const void* __restrict__ b_ih,
    const void* __restrict__ W_hh, const void* __restrict__ b_hh,
    float* __restrict__ out, const void* __restrict__ cosm, const int level)
{
    extern __shared__ char smem[];
    float* hs   = (float*)smem;                      // [64][132] = 33792 B
    float* bufA = (float*)(smem + 33792);            // [8][385] epilogue (gi)
    float* bufB = (float*)(smem + 33792 + 12320);    // [8][385] epilogue (gh)

    __shared__ int selr[K_TOP], selp[K_TOP];
    __shared__ int s_isbf;

    const int tid = threadIdx.x;
    const int b   = blockIdx.x;

    detect_bf16(cosm, tid, &s_isbf);
    const bool isbf = (bool)s_isbf;

    if (tid < K_TOP) {
        size_t rbase;
        if (level == 1)      rbase = TE_OFF + ((size_t)b * 3 + 1) * ROWSZ + K_TOP;
        else if (level == 2) rbase = TE_OFF + ((size_t)b * 3 + 2) * ROWSZ + K_TOP;
        else                 rbase = AR_OFF + ((size_t)b * 3 + 2) * K_TOP;
        selr[tid] = (int)out[rbase + tid];
        if (level >= 2) {
            size_t pbase = PI_OFF + ((size_t)b * 3 + (level - 2)) * K_TOP;
            selp[tid] = (int)out[pbase + tid];
        }
    }
    __syncthreads();

    const int gi_ = tid & 7;
    const int gj  = tid >> 3;  // 0..95

    // ---- GEMM 1: gi = rel_emb[selr] (64x128) @ W_ih^T (384x128) ----
    for (int idx = tid; idx < K_TOP * D; idx += 768) {
        int i = idx >> 7, d = idx & 127;
        hs[i * 132 + d] = ldin(rel_emb, (size_t)selr[i] * D + d, isbf);
    }
    __syncthreads();

    float accA[8][4];
    #pragma unroll
    for (int m = 0; m < 8; m++)
        #pragma unroll
        for (int n = 0; n < 4; n++) accA[m][n] = 0.f;
    gemm_8x4(hs, W_ih, isbf, gi_, gj, accA);

    // ---- GEMM 2 (level>=2): gh = h_parent (64x128) @ W_hh^T ----
    float accB[8][4];
    #pragma unroll
    for (int m = 0; m < 8; m++)
        #pragma unroll
        for (int n = 0; n < 4; n++) accB[m][n] = 0.f;

    if (level >= 2) {
        __syncthreads();   // everyone done reading hs (GEMM1)
        const float* hrow = out + TE_OFF + ((size_t)b * 3 + (level - 2)) * ROWSZ;
        for (int idx = tid; idx < K_TOP * D; idx += 768) {
            int i = idx >> 7, d = idx & 127;
            hs[i * 132 + d] = hrow[selp[i] * D + d];
        }
        __syncthreads();
        gemm_8x4(hs, W_hh, isbf, gi_, gj, accB);
    }

    float bih[4];
    #pragma unroll
    for (int n = 0; n < 4; n++) bih[n] = ldin(b_ih, gj + 96 * n, isbf);

    // ---- epilogue: gates in 8-node chunks via LDS transpose ----
    for (int c = 0; c < 8; c++) {
        __syncthreads();
        #pragma unroll
        for (int n = 0; n < 4; n++) {
            bufA[gi_ * 385 + gj + 96 * n] = accA[c][n] + bih[n];
            bufB[gi_ * 385 + gj + 96 * n] = (level >= 2) ? accB[c][n] : 0.f;
        }
        __syncthreads();
        for (int idx = tid; idx < 8 * D; idx += 768) {
            int iloc = idx >> 7, d = idx & 127;
            int node = 8 * c + iloc;
            float i_r = bufA[iloc * 385 + d];
            float i_z = bufA[iloc * 385 + 128 + d];
            float i_n = bufA[iloc * 385 + 256 + d];
            float h_r = bufB[iloc * 385 + d] + ldin(b_hh, d, isbf);
            float h_z = bufB[iloc * 385 + 128 + d] + ldin(b_hh, D + d, isbf);
            float h_n = bufB[iloc * 385 + 256 + d] + ldin(b_hh, 2 * D + d, isbf);
            float rg = 1.f / (1.f + expf(-(i_r + h_r)));
            float z  = 1.f / (1.f + expf(-(i_z + h_z)));
            float nn = tanhf(i_n + rg * h_n);
            float hprev = (level >= 2) ? hs[node * 132 + d] : 0.f;
            out[TE_OFF + ((size_t)b * 3 + (level - 1)) * ROWSZ + node * D + d]
                = (1.f - z) * nn + z * hprev;
        }
    }
}

// ---------------------------------------------------------------------------
extern "C" void kernel_launch(void* const* d_in, const int* in_sizes, int n_in,
                              void* d_out, int out_size, void* d_ws, size_t ws_size,
                              hipStream_t stream)
{
    const int*  query   = (const int*)d_in[0];
    const int*  edge    = (const int*)d_in[1];
    const int*  support = (const int*)d_in[2];
    const void* cosm    = d_in[3];   // f32 or bf16 -- detected on device
    const void* rel_emb = d_in[4];
    const void* W_ih    = d_in[5];
    const void* W_hh    = d_in[6];
    const void* b_ih    = d_in[7];
    const void* b_hh    = d_in[8];
    float* out = (float*)d_out;

    int* rnk = (int*)d_ws;  // 5000 int32 = 20 KB

    k_rank<<<(NUM_REL + 255) / 256, 256, 0, stream>>>(support, cosm, rnk);
    k_expand1<<<NB, 256, 0, stream>>>(query, edge, rnk, out);
    k_gru<<<NB, 768, 58432, stream>>>(rel_emb, W_ih, b_ih, W_hh, b_hh,
                                      out, cosm, 1);
    k_expand<<<NB, 384, 0, stream>>>(edge, rnk, out, 2);
    k_gru<<<NB, 768, 58432, stream>>>(rel_emb, W_ih, b_ih, W_hh, b_hh,
                                      out, cosm, 2);
    k_expand<<<NB, 384, 0, stream>>>(edge, rnk, out, 3);
    k_gru<<<NB, 768, 58432, stream>>>(rel_emb, W_ih, b_ih, W_hh, b_hh,
                                      out, cosm, 3);
}

// Round 6
// 622.178 us; speedup vs baseline: 1.3073x; 1.3073x over previous
//
#include <hip/hip_runtime.h>
#include <hip/hip_bf16.h>

#define NEI     128
#define NUM_REL 5000
#define NSUP    32
#define D       128
#define K_TOP   64
#define NB      256
#define ROWSZ   (K_TOP * D)   // 8192

// d_out layout (FLOAT32 elements), outputs concatenated flat in return order
#define TN_OFF  0           // tree_node      [256][3][64]
#define TE_OFF  49152       // tree_emb_all   [256][3][64][128]
#define PI_OFF  6340608     // parent_index   [256][3][64]
#define PN_OFF  6389760     // parent_node    [256][3][64]
#define AR_OFF  6438912     // aim_rel_all    [256][3][64]

#define SENT 0xFFFFFFFFu

typedef __hip_bfloat16 bf16;
__device__ __forceinline__ float frbf(bf16 b) { return __bfloat162float(b); }
__device__ __forceinline__ float b2f(unsigned short u) {
    unsigned x = ((unsigned)u) << 16;
    return __uint_as_float(x);
}
__device__ __forceinline__ unsigned umin2(unsigned a, unsigned b) { return a < b ? a : b; }

// Flag-dispatched float-input load: storage is either f32 or packed bf16.
__device__ __forceinline__ float ldin(const void* p, size_t idx, bool isbf) {
    return isbf ? frbf(((const bf16*)p)[idx]) : ((const float*)p)[idx];
}

// Detect storage dtype of float-family inputs (probe cosm); whole-block call.
__device__ __forceinline__ void detect_bf16(const void* probe, int tid, int* s_flag) {
    if (tid < 64) {
        unsigned w = ((const unsigned*)probe)[tid];
        unsigned e = (w >> 7) & 0xFFu;
        unsigned long long m = __ballot(e >= 100 && e <= 135);
        if (tid == 0) *s_flag = (__popcll(m) >= 48) ? 1 : 0;
    }
    __syncthreads();
}

// ---------------------------------------------------------------------------
// bf16 GEMM, W LDS-tiled in 4 quarters of 96 rows. X (64x128 f32) in hs.
// wq: ushort LDS region, row stride 136 ushorts (272 B -> 8 consecutive rows
// land in 8 distinct banks; reads are 8-lane same-address broadcasts).
// Inner K-loop touches ONLY LDS: no vmcnt waits, no barriers.
// acc[m][n] accumulation order per output element: kt ascending, dot4 chunks
// -- bit-identical to the verified round-3 kernel.
__device__ __forceinline__ void gemm_tiled_bf16(const float* hs, char* wq,
                                                const ushort* Wb, int tid,
                                                int gi_, int gj, float acc[8][8]) {
    for (int q = 0; q < 4; q++) {
        __syncthreads();   // previous readers of wq done
        const uint4* Wg = (const uint4*)(Wb + (size_t)96 * q * D); // 16 uint4/row
        for (int t = tid; t < 1536; t += 384) {
            int row = t >> 4, c = t & 15;
            *(uint4*)(wq + row * 272 + c * 16) = Wg[row * 16 + c];
        }
        __syncthreads();
        const int n0 = 2 * q;
        #pragma unroll 2
        for (int kt = 0; kt < D; kt += 4) {
            ushort4 t0 = *(const ushort4*)(wq + gj * 272 + kt * 2);
            ushort4 t1 = *(const ushort4*)(wq + (gj + 48) * 272 + kt * 2);
            float4 wv0 = make_float4(b2f(t0.x), b2f(t0.y), b2f(t0.z), b2f(t0.w));
            float4 wv1 = make_float4(b2f(t1.x), b2f(t1.y), b2f(t1.z), b2f(t1.w));
            float4 hv[8];
            #pragma unroll
            for (int m = 0; m < 8; m++)
                hv[m] = *(const float4*)&hs[(gi_ + 8 * m) * 132 + kt];
            #pragma unroll
            for (int m = 0; m < 8; m++) {
                acc[m][n0]     += hv[m].x * wv0.x + hv[m].y * wv0.y
                                + hv[m].z * wv0.z + hv[m].w * wv0.w;
                acc[m][n0 + 1] += hv[m].x * wv1.x + hv[m].y * wv1.y
                                + hv[m].z * wv1.z + hv[m].w * wv1.w;
            }
        }
    }
}

// f32 fallback: barrier-free global-stream GEMM (round-3 verified path).
__device__ __forceinline__ void gemm_glob_f32(const float* hs, const float* Wf,
                                              int gi_, int gj, float acc[8][8]) {
    #pragma unroll 2
    for (int kt = 0; kt < D; kt += 4) {
        float4 hv[8], wv[8];
        #pragma unroll
        for (int n = 0; n < 8; n++)
            wv[n] = *(const float4*)&Wf[(size_t)(gj + 48 * n) * D + kt];
        #pragma unroll
        for (int m = 0; m < 8; m++)
            hv[m] = *(const float4*)&hs[(gi_ + 8 * m) * 132 + kt];
        #pragma unroll
        for (int m = 0; m < 8; m++)
            #pragma unroll
            for (int n = 0; n < 8; n++)
                acc[m][n] += hv[m].x * wv[n].x + hv[m].y * wv[n].y
                           + hv[m].z * wv[n].z + hv[m].w * wv[n].w;
    }
}

// ---------------------------------------------------------------------------
// rank[r] = #{r' : maxscore[r'] > maxscore[r]} (ties share rank ->
// key (rank<<13|idx) reproduces jax.lax.top_k ordering exactly). Vectorized.
__global__ __launch_bounds__(256) void k_rank(const int* __restrict__ support,
                                              const void* __restrict__ cosm,
                                              int* __restrict__ rnk) {
    __shared__ __align__(16) float ms[NUM_REL];
    __shared__ int sup[NSUP];
    __shared__ int s_isbf;
    const int tid = threadIdx.x;
    detect_bf16(cosm, tid, &s_isbf);
    const bool isbf = (bool)s_isbf;
    if (tid < NSUP) sup[tid] = support[tid];
    __syncthreads();

    float4* ms4 = (float4*)ms;
    const int NC4 = NUM_REL / 4;  // 1250, exact
    if (!isbf) {
        const float* cf = (const float*)cosm;
        for (int i4 = tid; i4 < NC4; i4 += 256) {
            float4 m = make_float4(-INFINITY, -INFINITY, -INFINITY, -INFINITY);
            #pragma unroll
            for (int s = 0; s < NSUP; s++) {
                float4 v = *(const float4*)&cf[(size_t)sup[s] * NUM_REL + i4 * 4];
                m.x = fmaxf(m.x, v.x); m.y = fmaxf(m.y, v.y);
                m.z = fmaxf(m.z, v.z); m.w = fmaxf(m.w, v.w);
            }
            ms4[i4] = m;
        }
    } else {
        const ushort* cb = (const ushort*)cosm;
        for (int i4 = tid; i4 < NC4; i4 += 256) {
            float4 m = make_float4(-INFINITY, -INFINITY, -INFINITY, -INFINITY);
            #pragma unroll
            for (int s = 0; s < NSUP; s++) {
                ushort4 t = *(const ushort4*)&cb[(size_t)sup[s] * NUM_REL + i4 * 4];
                m.x = fmaxf(m.x, b2f(t.x)); m.y = fmaxf(m.y, b2f(t.y));
                m.z = fmaxf(m.z, b2f(t.z)); m.w = fmaxf(m.w, b2f(t.w));
            }
            ms4[i4] = m;
        }
    }
    __syncthreads();

    int r = blockIdx.x * 256 + tid;
    if (r < NUM_REL) {
        float mine = ms[r];
        int c = 0;
        for (int i4 = 0; i4 < NC4; i4++) {
            float4 v = ms4[i4];
            c += (v.x > mine) + (v.y > mine) + (v.z > mine) + (v.w > mine);
        }
        rnk[r] = c;
    }
}

// ---------------------------------------------------------------------------
// Level-1 selection only: 128 candidates -> stable top-64 via bitonic sort.
__global__ __launch_bounds__(256) void k_expand1(
    const int* __restrict__ query, const int* __restrict__ edge,
    const int* __restrict__ rnk, float* __restrict__ out)
{
    __shared__ unsigned keys[NEI];
    __shared__ int2 pairs[NEI];
    const int tid = threadIdx.x;
    const int b = blockIdx.x;
    const int q = query[b];

    if (tid < NEI) {
        int2 pr = ((const int2*)edge)[(size_t)q * NEI + tid];
        pairs[tid] = pr;
        keys[tid] = ((unsigned)rnk[pr.y] << 13) | (unsigned)tid;
    }
    for (int size = 2; size <= NEI; size <<= 1) {
        for (int stride = size >> 1; stride > 0; stride >>= 1) {
            __syncthreads();
            if (tid < NEI) {
                int partner = tid ^ stride;
                if (partner > tid) {
                    unsigned a = keys[tid], c2 = keys[partner];
                    bool asc = ((tid & size) == 0);
                    if (asc ? (a > c2) : (a < c2)) { keys[tid] = c2; keys[partner] = a; }
                }
            }
        }
    }
    __syncthreads();
    if (tid < K_TOP) {
        int idx = keys[tid] & 8191;
        int2 p = pairs[idx];
        float* su = out + TE_OFF + ((size_t)b * 3 + 1) * ROWSZ;
        su[tid]         = (float)p.x;   // e1 (exact in f32)
        su[K_TOP + tid] = (float)p.y;   // r1
        out[TN_OFF + (b * 3 + 0) * K_TOP + tid] = (float)p.x;
        out[PN_OFF + (b * 3 + 0) * K_TOP + tid] = (float)q;
        out[PI_OFF + (b * 3 + 2) * K_TOP + tid] = (float)tid;  // arange row
    }
}

// ---------------------------------------------------------------------------
// Levels 2/3 selection: 8192 candidates -> top-64 (register keys, iterative
// block-min). Level 2 stashes (e2,r2) in TE row 2 head.
__global__ __launch_bounds__(384) void k_expand(
    const int* __restrict__ edge, const int* __restrict__ rnk,
    float* __restrict__ out, const int level)
{
    __shared__ int pe[K_TOP], prl[K_TOP];
    __shared__ unsigned topks[K_TOP];
    __shared__ unsigned wred[6];

    const int tid = threadIdx.x;
    const int b = blockIdx.x;
    const int2* edge2 = (const int2*)edge;

    if (tid < K_TOP) {
        const float* su = out + TE_OFF + ((size_t)b * 3 + (level - 1)) * ROWSZ;
        pe[tid]  = (int)su[tid];
        prl[tid] = (int)su[K_TOP + tid];
    }
    __syncthreads();

    unsigned kreg[22];
    #pragma unroll
    for (int i = 0; i < 22; i++) {
        int j = tid + i * 384;
        unsigned k = SENT;
        if (j < K_TOP * NEI) {
            int rel = edge2[(size_t)pe[j >> 7] * NEI + (j & 127)].y;
            k = ((unsigned)rnk[rel] << 13) | (unsigned)j;
        }
        kreg[i] = k;
    }
    unsigned lmin = SENT;
    #pragma unroll
    for (int i = 0; i < 22; i++) lmin = umin2(lmin, kreg[i]);

    const int wid = tid >> 6;
    for (int it = 0; it < K_TOP; it++) {
        unsigned m = lmin;
        #pragma unroll
        for (int off = 32; off > 0; off >>= 1)
            m = umin2(m, (unsigned)__shfl_xor((int)m, off, 64));
        if ((tid & 63) == 0) wred[wid] = m;
        __syncthreads();
        unsigned g = umin2(umin2(umin2(wred[0], wred[1]), umin2(wred[2], wred[3])),
                           umin2(wred[4], wred[5]));
        if (tid == 0) topks[it] = g;
        if (lmin == g) {
            unsigned nl = SENT;
            #pragma unroll
            for (int i = 0; i < 22; i++) {
                if (kreg[i] == g) kreg[i] = SENT;
                nl = umin2(nl, kreg[i]);
            }
            lmin = nl;
        }
        __syncthreads();
    }

    if (tid < K_TOP) {
        int j = topks[tid] & 8191;
        int p = j >> 7, t = j & 127;
        int2 pr2 = edge2[(size_t)pe[p] * NEI + t];
        const int L1 = level - 1;
        out[TN_OFF + (b * 3 + L1) * K_TOP + tid]          = (float)pr2.x;
        out[PI_OFF + (b * 3 + (level - 2)) * K_TOP + tid] = (float)p;
        out[PN_OFF + (b * 3 + L1) * K_TOP + tid]          = (float)pe[p];
        out[AR_OFF + (b * 3 + (level - 2)) * K_TOP + tid] = (float)prl[p];
        if (level == 3)
            out[AR_OFF + (b * 3 + 2) * K_TOP + tid]       = (float)pr2.y;
        if (level == 2) {
            float* su = out + TE_OFF + ((size_t)b * 3 + 2) * ROWSZ;
            su[tid]         = (float)pr2.x;
            su[K_TOP + tid] = (float)pr2.y;
        }
    }
}

// ---------------------------------------------------------------------------
// GRU for one level. One 384-thread block per batch (round-3 verified shape).
// bf16 path: W staged in LDS quarters -> inner K-loop is LDS-only (no vmcnt
// stalls). f32 path: round-3 global-stream. b_hh staged in LDS for epilogue.
// Dynamic LDS: hs [64][132] f32 (33792) + wq [96][136] ushort (26112) = 59904;
// epilogue bufA/bufB (2x12320) overlay wq after the GEMMs.
__global__ __launch_bounds__(384) void k_gru(
    const void* __restrict__ rel_emb,
    const void* __restrict__ W_ih, const void* __restrict__ b_ih,
    const void* __restrict__ W_hh, const void* __restrict__ b_hh,
    float* __restrict__ out, const void* __restrict__ cosm, const int level)
{
    extern __shared__ char smem[];
    float* hs   = (float*)smem;                      // [64][132] = 33792 B
    char*  wq   = smem + 33792;                      // [96][136] ushort = 26112
    float* bufA = (float*)(smem + 33792);            // [8][385] epilogue (gi)
    float* bufB = (float*)(smem + 33792 + 12320);    // [8][385] epilogue (gh)

    __shared__ int selr[K_TOP], selp[K_TOP];
    __shared__ float sbhh[3 * D];
    __shared__ int s_isbf;

    const int tid = threadIdx.x;
    const int b   = blockIdx.x;

    detect_bf16(cosm, tid, &s_isbf);
    const bool isbf = (bool)s_isbf;

    if (tid < K_TOP) {
        size_t rbase;
        if (level == 1)      rbase = TE_OFF + ((size_t)b * 3 + 1) * ROWSZ + K_TOP;
        else if (level == 2) rbase = TE_OFF + ((size_t)b * 3 + 2) * ROWSZ + K_TOP;
        else                 rbase = AR_OFF + ((size_t)b * 3 + 2) * K_TOP;
        selr[tid] = (int)out[rbase + tid];
        if (level >= 2) {
            size_t pbase = PI_OFF + ((size_t)b * 3 + (level - 2)) * K_TOP;
            selp[tid] = (int)out[pbase + tid];
        }
    }
    if (tid < 3 * D) sbhh[tid] = ldin(b_hh, tid, isbf);
    __syncthreads();

    const int gi_ = tid & 7;
    const int gj  = tid >> 3;  // 0..47

    // ---- GEMM 1: gi = rel_emb[selr] (64x128) @ W_ih^T (384x128) ----
    for (int idx = tid; idx < K_TOP * D; idx += 384) {
        int i = idx >> 7, d = idx & 127;
        hs[i * 132 + d] = ldin(rel_emb, (size_t)selr[i] * D + d, isbf);
    }
    __syncthreads();

    float accA[8][8];
    #pragma unroll
    for (int m = 0; m < 8; m++)
        #pragma unroll
        for (int n = 0; n < 8; n++) accA[m][n] = 0.f;
    if (isbf) gemm_tiled_bf16(hs, wq, (const ushort*)W_ih, tid, gi_, gj, accA);
    else      gemm_glob_f32(hs, (const float*)W_ih, gi_, gj, accA);

    // ---- GEMM 2 (level>=2): gh = h_parent (64x128) @ W_hh^T ----
    float accB[8][8];
    #pragma unroll
    for (int m = 0; m < 8; m++)
        #pragma unroll
        for (int n = 0; n < 8; n++) accB[m][n] = 0.f;

    if (level >= 2) {
        __syncthreads();   // everyone done reading hs (GEMM1)
        const float* hrow = out + TE_OFF + ((size_t)b * 3 + (level - 2)) * ROWSZ;
        for (int idx = tid; idx < K_TOP * D; idx += 384) {
            int i = idx >> 7, d = idx & 127;
            hs[i * 132 + d] = hrow[selp[i] * D + d];
        }
        __syncthreads();
        if (isbf) gemm_tiled_bf16(hs, wq, (const ushort*)W_hh, tid, gi_, gj, accB);
        else      gemm_glob_f32(hs, (const float*)W_hh, gi_, gj, accB);
    }

    float bih[8];
    #pragma unroll
    for (int n = 0; n < 8; n++) bih[n] = ldin(b_ih, gj + 48 * n, isbf);

    // ---- epilogue: gates in 8-node chunks via LDS transpose ----
    for (int c = 0; c < 8; c++) {
        __syncthreads();
        #pragma unroll
        for (int n = 0; n < 8; n++) {
            bufA[gi_ * 385 + gj + 48 * n] = accA[c][n] + bih[n];
            bufB[gi_ * 385 + gj + 48 * n] = (level >= 2) ? accB[c][n] : 0.f;
        }
        __syncthreads();
        for (int idx = tid; idx < 8 * D; idx += 384) {
            int iloc = idx >> 7, d = idx & 127;
            int node = 8 * c + iloc;
            float i_r = bufA[iloc * 385 + d];
            float i_z = bufA[iloc * 385 + 128 + d];
            float i_n = bufA[iloc * 385 + 256 + d];
            float h_r = bufB[iloc * 385 + d] + sbhh[d];
            float h_z = bufB[iloc * 385 + 128 + d] + sbhh[D + d];
            float h_n = bufB[iloc * 385 + 256 + d] + sbhh[2 * D + d];
            float rg = 1.f / (1.f + expf(-(i_r + h_r)));
            float z  = 1.f / (1.f + expf(-(i_z + h_z)));
            float nn = tanhf(i_n + rg * h_n);
            float hprev = (level >= 2) ? hs[node * 132 + d] : 0.f;
            out[TE_OFF + ((size_t)b * 3 + (level - 1)) * ROWSZ + node * D + d]
                = (1.f - z) * nn + z * hprev;
        }
    }
}

// ---------------------------------------------------------------------------
extern "C" void kernel_launch(void* const* d_in, const int* in_sizes, int n_in,
                              void* d_out, int out_size, void* d_ws, size_t ws_size,
                              hipStream_t stream)
{
    const int*  query   = (const int*)d_in[0];
    const int*  edge    = (const int*)d_in[1];
    const int*  support = (const int*)d_in[2];
    const void* cosm    = d_in[3];   // f32 or bf16 -- detected on device
    const void* rel_emb = d_in[4];
    const void* W_ih    = d_in[5];
    const void* W_hh    = d_in[6];
    const void* b_ih    = d_in[7];
    const void* b_hh    = d_in[8];
    float* out = (float*)d_out;

    int* rnk = (int*)d_ws;  // 5000 int32 = 20 KB

    k_rank<<<(NUM_REL + 255) / 256, 256, 0, stream>>>(support, cosm, rnk);
    k_expand1<<<NB, 256, 0, stream>>>(query, edge, rnk, out);
    k_gru<<<NB, 384, 59904, stream>>>(rel_emb, W_ih, b_ih, W_hh, b_hh,
                                      out, cosm, 1);
    k_expand<<<NB, 384, 0, stream>>>(edge, rnk, out, 2);
    k_gru<<<NB, 384, 59904, stream>>>(rel_emb, W_ih, b_ih, W_hh, b_hh,
                                      out, cosm, 2);
    k_expand<<<NB, 384, 0, stream>>>(edge, rnk, out, 3);
    k_gru<<<NB, 384, 59904, stream>>>(rel_emb, W_ih, b_ih, W_hh, b_hh,
                                      out, cosm, 3);
}